// Round 2
// baseline (1698.918 us; speedup 1.0000x reference)
//
#include <hip/hip_runtime.h>

// Problem constants
// B=16, S=38 -> ROWS=608; D=1792; H=4, DK=448; NP=128; INF=768
#define BM 64
#define BN 64
#define BK 16

// Generic fp32 tiled GEMM: C[M,N] = A[M,K] @ op(B) + bias (+ C if accumulate)
// TRANSB=false: B is [K,N] row-major (ldb = row stride of B)
// TRANSB=true : B is [N,K] row-major (ldb = row stride of B); C[m,n] = sum_k A[m,k]*B[n,k]
template<bool TRANSB>
__global__ __launch_bounds__(256) void gemm_tile(
    const float* __restrict__ A, int lda,
    const float* __restrict__ B, int ldb,
    float* __restrict__ C, int ldc,
    const float* __restrict__ bias,
    int M, int N, int K, int accumulate)
{
    __shared__ float As[BK][BM + 1];
    __shared__ float Bs[BK][BN + 1];

    const int tid = threadIdx.x;
    const int tx = tid & 15;          // N direction (4 cols each)
    const int ty = tid >> 4;          // M direction (4 rows each)
    const int rowBase = blockIdx.y * BM;
    const int colBase = blockIdx.x * BN;

    float acc[4][4] = {};

    const int numK = K / BK;          // all K here are multiples of 16
    for (int kt = 0; kt < numK; ++kt) {
        const int k0 = kt * BK;
        // ---- load A tile (BM x BK), stored transposed As[k][m]
        {
            const int c = tid & (BK - 1);   // k within tile
            const int r0 = tid >> 4;        // m within tile (0..15)
            #pragma unroll
            for (int it = 0; it < 4; ++it) {
                const int r = r0 + it * 16;
                const int grow = rowBase + r;
                float v = 0.f;
                if (grow < M) v = A[(long)grow * lda + k0 + c];
                As[c][r] = v;
            }
        }
        // ---- load B tile
        if (!TRANSB) {
            const int c = tid & (BN - 1);   // n within tile
            const int r0 = tid >> 6;        // k within tile (0..3)
            #pragma unroll
            for (int it = 0; it < 4; ++it) {
                const int r = r0 + it * 4;
                const int gcol = colBase + c;
                float v = 0.f;
                if (gcol < N) v = B[(long)(k0 + r) * ldb + gcol];
                Bs[r][c] = v;
            }
        } else {
            const int c = tid & (BK - 1);   // k within tile
            const int r0 = tid >> 4;        // n within tile (0..15)
            #pragma unroll
            for (int it = 0; it < 4; ++it) {
                const int r = r0 + it * 16;
                const int gn = colBase + r;
                float v = 0.f;
                if (gn < N) v = B[(long)gn * ldb + k0 + c];
                Bs[c][r] = v;
            }
        }
        __syncthreads();

        #pragma unroll
        for (int kk = 0; kk < BK; ++kk) {
            float a[4], b[4];
            #pragma unroll
            for (int i = 0; i < 4; ++i) a[i] = As[kk][ty * 4 + i];
            #pragma unroll
            for (int j = 0; j < 4; ++j) b[j] = Bs[kk][tx * 4 + j];
            #pragma unroll
            for (int i = 0; i < 4; ++i)
                #pragma unroll
                for (int j = 0; j < 4; ++j)
                    acc[i][j] = fmaf(a[i], b[j], acc[i][j]);
        }
        __syncthreads();
    }

    #pragma unroll
    for (int i = 0; i < 4; ++i) {
        const int row = rowBase + ty * 4 + i;
        if (row >= M) continue;
        #pragma unroll
        for (int j = 0; j < 4; ++j) {
            const int col = colBase + tx * 4 + j;
            if (col >= N) continue;
            float v = acc[i][j];
            if (bias) v += bias[col];
            const long idx = (long)row * ldc + col;
            if (accumulate) v += C[idx];
            C[idx] = v;
        }
    }
}

// For each (head, row): argmax over 128 prototype scores, then copy that
// prototype's V head-slice (448 floats) into X2[row, head*448 ...].
__global__ __launch_bounds__(256) void argmax_gather(
    const float* __restrict__ scores,   // [4][ROWS][128]
    const float* __restrict__ Vp,       // [128][1792]
    float* __restrict__ X2,             // [ROWS][1792]
    int rows)
{
    const int lane = threadIdx.x & 63;
    const int w = threadIdx.x >> 6;
    const int unit = blockIdx.x * 4 + w;
    if (unit >= rows * 4) return;
    const int h = unit & 3;
    const int row = unit >> 2;

    const float* sc = scores + ((long)h * rows + row) * 128;
    float v0 = sc[lane];
    float v1 = sc[lane + 64];
    float best = v0; int bi = lane;
    if (v1 > best) { best = v1; bi = lane + 64; }
    #pragma unroll
    for (int off = 32; off >= 1; off >>= 1) {
        float ov = __shfl_down(best, off);
        int   oi = __shfl_down(bi, off);
        if (ov > best || (ov == best && oi < bi)) { best = ov; bi = oi; }
    }
    bi = __shfl(bi, 0);   // broadcast winner index

    const float* src = Vp + (long)bi * 1792 + h * 448;
    float* dst = X2 + (long)row * 1792 + h * 448;
    #pragma unroll
    for (int j = 0; j < 7; ++j)
        dst[lane + j * 64] = src[lane + j * 64];
}

// logits[row, 0:2] = reduced[row, :768] @ Wqa[768,2] + bqa
__global__ __launch_bounds__(256) void logits_kernel(
    const float* __restrict__ red,   // [ROWS][768]
    const float* __restrict__ Wqa,   // [768][2]
    const float* __restrict__ bqa,   // [2]
    float* __restrict__ out,         // [ROWS][2]
    int rows)
{
    const int lane = threadIdx.x & 63;
    const int w = threadIdx.x >> 6;
    const int row = blockIdx.x * 4 + w;
    if (row >= rows) return;
    const float* r = red + (long)row * 768;
    float a0 = 0.f, a1 = 0.f;
    #pragma unroll
    for (int i = 0; i < 12; ++i) {
        const int k = lane + i * 64;
        const float x = r[k];
        a0 = fmaf(x, Wqa[k * 2 + 0], a0);
        a1 = fmaf(x, Wqa[k * 2 + 1], a1);
    }
    #pragma unroll
    for (int off = 32; off >= 1; off >>= 1) {
        a0 += __shfl_down(a0, off);
        a1 += __shfl_down(a1, off);
    }
    if (lane == 0) {
        out[row * 2 + 0] = a0 + bqa[0];
        out[row * 2 + 1] = a1 + bqa[1];
    }
}

extern "C" void kernel_launch(void* const* d_in, const int* in_sizes, int n_in,
                              void* d_out, int out_size, void* d_ws, size_t ws_size,
                              hipStream_t stream)
{
    const float* X     = (const float*)d_in[0];   // [16,38,1792]
    const float* proto = (const float*)d_in[1];   // [1,128,1792]
    // d_in[2] = attention_mask (unused by the reference)
    const float* Wq  = (const float*)d_in[3];
    const float* bq  = (const float*)d_in[4];
    const float* Wk  = (const float*)d_in[5];
    const float* bk  = (const float*)d_in[6];
    const float* Wv  = (const float*)d_in[7];
    const float* bv  = (const float*)d_in[8];
    const float* Wo  = (const float*)d_in[9];
    const float* bo  = (const float*)d_in[10];
    const float* Wfc = (const float*)d_in[11];    // [3584, 768]
    const float* bfc = (const float*)d_in[12];
    const float* Wqa = (const float*)d_in[13];    // [768, 2]
    const float* bqa = (const float*)d_in[14];
    float* out = (float*)d_out;                   // [608, 2] fp32

    const int D = 1792, NP = 128, ROWS = 16 * 38, INF = 768, DK = 448;

    float* ws = (float*)d_ws;
    float* Kp = ws;                    // [128,1792]
    float* Vp = Kp + NP * D;           // [128,1792]
    float* Q  = Vp + NP * D;           // [608,1792]
    float* Sc = Q + ROWS * D;          // [4][608][128]
    float* X2 = Sc + 4 * ROWS * NP;    // [608,1792]
    float* Rp = X2 + ROWS * D;         // [608,1792]
    float* Rd = Rp + ROWS * D;         // [608,768]

    dim3 blk(256);

    // K_proto = proto @ Wk + bk ; V_proto = proto @ Wv + bv
    gemm_tile<false><<<dim3(D / BN, (NP + BM - 1) / BM), blk, 0, stream>>>(
        proto, D, Wk, D, Kp, D, bk, NP, D, D, 0);
    gemm_tile<false><<<dim3(D / BN, (NP + BM - 1) / BM), blk, 0, stream>>>(
        proto, D, Wv, D, Vp, D, bv, NP, D, D, 0);

    // Q = X @ Wq + bq
    gemm_tile<false><<<dim3(D / BN, (ROWS + BM - 1) / BM), blk, 0, stream>>>(
        X, D, Wq, D, Q, D, bq, ROWS, D, D, 0);

    // scores[h] = Q_h [608,448] @ K_h^T [448,128]   (scale irrelevant for argmax)
    for (int h = 0; h < 4; ++h) {
        gemm_tile<true><<<dim3(NP / BN, (ROWS + BM - 1) / BM), blk, 0, stream>>>(
            Q + h * DK, D, Kp + h * DK, D, Sc + (long)h * ROWS * NP, NP,
            nullptr, ROWS, NP, DK, 0);
    }

    // per-(row,head) argmax over 128 + gather V slice
    argmax_gather<<<dim3((ROWS * 4 + 3) / 4), blk, 0, stream>>>(Sc, Vp, X2, ROWS);

    // response = X2 @ Wo + bo
    gemm_tile<false><<<dim3(D / BN, (ROWS + BM - 1) / BM), blk, 0, stream>>>(
        X2, D, Wo, D, Rp, D, bo, ROWS, D, D, 0);

    // reduced = X @ Wfc[0:1792] + bfc ; then += resp @ Wfc[1792:3584]
    gemm_tile<false><<<dim3(INF / BN, (ROWS + BM - 1) / BM), blk, 0, stream>>>(
        X, D, Wfc, INF, Rd, INF, bfc, ROWS, INF, D, 0);
    gemm_tile<false><<<dim3(INF / BN, (ROWS + BM - 1) / BM), blk, 0, stream>>>(
        Rp, D, Wfc + (long)D * INF, INF, Rd, INF, nullptr, ROWS, INF, D, 1);

    // logits = reduced @ Wqa + bqa
    logits_kernel<<<dim3((ROWS + 3) / 4), blk, 0, stream>>>(Rd, Wqa, bqa, out, ROWS);
}

// Round 3
// 212.051 us; speedup vs baseline: 8.0118x; 8.0118x over previous
//
#include <hip/hip_runtime.h>

// B=16,S=38 -> ROWS=608; D=1792; H=4, DK=448; NP=128; INF=768
#define BM 64
#define BN 64
#define BK 16
#define LDT 68   // padded LDS leading dim: 68*4=272 B, 16B-aligned rows

// C = A[M,K] @ op(B) ; optional K-split (partials) and batch (pointer strides).
// grid.z = nbatch*nsplit ; kb = z%nsplit, bb = z/nsplit.
// nsplit>1: write partial[kb][M][N] dense at C (ldc ignored). nsplit==1: C + bb*sCb, ldc.
template<bool TRANSB>
__global__ __launch_bounds__(256) void gemm_f32(
    const float* __restrict__ A, int lda,
    const float* __restrict__ B, int ldb,
    float* __restrict__ C, int ldc,
    int M, int N, int K, int nsplit,
    long sAb, long sBb, long sCb)
{
    const int kb = blockIdx.z % nsplit;
    const int bb = blockIdx.z / nsplit;
    A += sAb * bb;
    B += sBb * bb;
    const int Kc = K / nsplit;
    const int kbeg = kb * Kc;

    __shared__ float As[BK][LDT];
    __shared__ float Bs[BK][LDT];

    const int tid = threadIdx.x;
    const int tx = tid & 15, ty = tid >> 4;
    const int rowBase = blockIdx.y * BM;
    const int colBase = blockIdx.x * BN;

    // staging maps
    const int am  = tid >> 2;           // A row 0..63
    const int akq = (tid & 3) * 4;      // A k-quad
    const int bkr = tid >> 4;           // B k-row (TRANSB=false) 0..15
    const int bcq = (tid & 15) * 4;     // B col-quad
    const int bn  = tid >> 2;           // B n (TRANSB=true) 0..63
    const int bkq = (tid & 3) * 4;

    const long arow = (long)(rowBase + am) * lda;
    const bool aok = (rowBase + am) < M;

    auto loadA = [&](int k0) {
        float4 v = make_float4(0.f, 0.f, 0.f, 0.f);
        if (aok) v = *(const float4*)&A[arow + k0 + akq];
        return v;
    };
    auto loadB = [&](int k0) {
        if (!TRANSB) return *(const float4*)&B[(long)(k0 + bkr) * ldb + colBase + bcq];
        else         return *(const float4*)&B[(long)(colBase + bn) * ldb + k0 + bkq];
    };

    float4 av = loadA(kbeg), bv = loadB(kbeg);
    float acc[4][4] = {};

    for (int kt = 0; kt < Kc; kt += BK) {
        As[akq + 0][am] = av.x; As[akq + 1][am] = av.y;
        As[akq + 2][am] = av.z; As[akq + 3][am] = av.w;
        if (!TRANSB) {
            *(float4*)&Bs[bkr][bcq] = bv;
        } else {
            Bs[bkq + 0][bn] = bv.x; Bs[bkq + 1][bn] = bv.y;
            Bs[bkq + 2][bn] = bv.z; Bs[bkq + 3][bn] = bv.w;
        }
        __syncthreads();
        if (kt + BK < Kc) { av = loadA(kbeg + kt + BK); bv = loadB(kbeg + kt + BK); }
        #pragma unroll
        for (int kk = 0; kk < BK; ++kk) {
            float a[4], b[4];
            *(float4*)a = *(const float4*)&As[kk][ty * 4];
            *(float4*)b = *(const float4*)&Bs[kk][tx * 4];
            #pragma unroll
            for (int i = 0; i < 4; ++i)
                #pragma unroll
                for (int j = 0; j < 4; ++j)
                    acc[i][j] = fmaf(a[i], b[j], acc[i][j]);
        }
        __syncthreads();
    }

    float* Cw = (nsplit > 1) ? (C + (long)kb * M * N) : (C + sCb * bb);
    const int wldc = (nsplit > 1) ? N : ldc;
    #pragma unroll
    for (int i = 0; i < 4; ++i) {
        const int row = rowBase + ty * 4 + i;
        if (row >= M) continue;
        float4 v = make_float4(acc[i][0], acc[i][1], acc[i][2], acc[i][3]);
        *(float4*)&Cw[(long)row * wldc + colBase + tx * 4] = v;
    }
}

// out[i] = sum_z part[z*sz+i] (+ bias[i%N])
__global__ __launch_bounds__(256) void reduce_add(
    const float* __restrict__ part, float* __restrict__ out,
    const float* __restrict__ bias, int N, long sz, int nsplit)
{
    long i = (long)blockIdx.x * 256 + threadIdx.x;
    const long stride = (long)gridDim.x * 256;
    for (; i < sz; i += stride) {
        float s = 0.f;
        for (int z = 0; z < nsplit; ++z) s += part[z * sz + i];
        if (bias) s += bias[i % N];
        out[i] = s;
    }
}

// per (row,h): sum 4 partials over 128 protos + sbias -> argmax -> idx
__global__ __launch_bounds__(256) void score_argmax(
    const float* __restrict__ Spart,   // [4][608][512]
    const float* __restrict__ sbias,   // [512]
    int* __restrict__ idx)             // [608][4]
{
    const int lane = threadIdx.x & 63;
    const int unit = blockIdx.x * 4 + (threadIdx.x >> 6);
    if (unit >= 608 * 4) return;
    const int row = unit >> 2, h = unit & 3;
    const long base = (long)row * 512 + h * 128;
    float s0 = sbias[h * 128 + lane];
    float s1 = sbias[h * 128 + lane + 64];
    #pragma unroll
    for (int z = 0; z < 4; ++z) {
        s0 += Spart[z * (608L * 512) + base + lane];
        s1 += Spart[z * (608L * 512) + base + lane + 64];
    }
    float best = s0; int bi = lane;
    if (s1 > best) { best = s1; bi = lane + 64; }
    #pragma unroll
    for (int off = 32; off; off >>= 1) {
        float ov = __shfl_down(best, off);
        int   oi = __shfl_down(bi, off);
        if (ov > best || (ov == best && oi < bi)) { best = ov; bi = oi; }
    }
    if (lane == 0) idx[row * 4 + h] = bi;
}

// sbias[h*128+p] = dot(bq_h, Kp[p]_h) over 448
__global__ __launch_bounds__(256) void sbias_k(
    const float* __restrict__ bq, const float* __restrict__ Kp,
    float* __restrict__ sbias)
{
    const int lane = threadIdx.x & 63;
    const int unit = blockIdx.x * 4 + (threadIdx.x >> 6);
    if (unit >= 512) return;
    const int h = unit >> 7, p = unit & 127;
    const float* kr = Kp + (long)p * 1792 + h * 448;
    const float* bh = bq + h * 448;
    float s = 0.f;
    #pragma unroll
    for (int i = 0; i < 7; ++i) s = fmaf(bh[lane + 64 * i], kr[lane + 64 * i], s);
    #pragma unroll
    for (int off = 32; off; off >>= 1) s += __shfl_down(s, off);
    if (lane == 0) sbias[unit] = s;
}

// LG[r][c] = dot(RF[r][0..767], Wqa[:,c])
__global__ __launch_bounds__(256) void lg_k(
    const float* __restrict__ RF, const float* __restrict__ Wqa,
    float* __restrict__ LG)
{
    const int lane = threadIdx.x & 63;
    const int r = blockIdx.x * 4 + (threadIdx.x >> 6);
    if (r >= 512) return;
    const float4* x = (const float4*)(RF + (long)r * 768);
    float a0 = 0.f, a1 = 0.f;
    #pragma unroll
    for (int i = 0; i < 3; ++i) {
        const int d4 = lane + 64 * i;
        float4 xv = x[d4];
        const float4* w = (const float4*)(Wqa + (long)d4 * 8);
        float4 w0 = w[0], w1 = w[1];
        a0 += xv.x * w0.x + xv.y * w0.z + xv.z * w1.x + xv.w * w1.z;
        a1 += xv.x * w0.y + xv.y * w0.w + xv.z * w1.y + xv.w * w1.w;
    }
    #pragma unroll
    for (int off = 32; off; off >>= 1) { a0 += __shfl_down(a0, off); a1 += __shfl_down(a1, off); }
    if (lane == 0) { LG[r * 2 + 0] = a0; LG[r * 2 + 1] = a1; }
}

// bvec[j] = bfc[j] + sum_k bo[k]*Wfc[(1792+k)*768 + j]
__global__ __launch_bounds__(256) void bvec_k(
    const float* __restrict__ bo, const float* __restrict__ Wfc,
    const float* __restrict__ bfc, float* __restrict__ bvec)
{
    __shared__ float red[4][64];
    const int lane = threadIdx.x & 63;
    const int w = threadIdx.x >> 6;
    const int j = blockIdx.x * 64 + lane;
    const float* Wb = Wfc + 1792L * 768;
    float s = 0.f;
    for (int k = w * 448; k < (w + 1) * 448; ++k)
        s = fmaf(bo[k], Wb[(long)k * 768 + j], s);
    red[w][lane] = s;
    __syncthreads();
    if (w == 0) bvec[j] = red[0][lane] + red[1][lane] + red[2][lane] + red[3][lane] + bfc[j];
}

// units 0..1791: Wbig[m][c] = dot(Wfc_top[m], Wqa[:,c]); unit 1792: const2 = bvec@Wqa + bqa
__global__ __launch_bounds__(256) void wbig_k(
    const float* __restrict__ Wfc, const float* __restrict__ Wqa,
    const float* __restrict__ bvec, const float* __restrict__ bqa,
    float* __restrict__ Wbig, float* __restrict__ const2)
{
    const int lane = threadIdx.x & 63;
    const int m = blockIdx.x * 4 + (threadIdx.x >> 6);
    if (m > 1792) return;
    const float4* x = (const float4*)((m < 1792) ? (Wfc + (long)m * 768) : bvec);
    float a0 = 0.f, a1 = 0.f;
    #pragma unroll
    for (int i = 0; i < 3; ++i) {
        const int d4 = lane + 64 * i;
        float4 xv = x[d4];
        const float4* w = (const float4*)(Wqa + (long)d4 * 8);
        float4 w0 = w[0], w1 = w[1];
        a0 += xv.x * w0.x + xv.y * w0.z + xv.z * w1.x + xv.w * w1.z;
        a1 += xv.x * w0.y + xv.y * w0.w + xv.z * w1.y + xv.w * w1.w;
    }
    #pragma unroll
    for (int off = 32; off; off >>= 1) { a0 += __shfl_down(a0, off); a1 += __shfl_down(a1, off); }
    if (lane == 0) {
        if (m < 1792) { Wbig[m * 2 + 0] = a0; Wbig[m * 2 + 1] = a1; }
        else          { const2[0] = a0 + bqa[0]; const2[1] = a1 + bqa[1]; }
    }
}

// logits[row][c] = dot(X[row], Wbig[:,c]) + sum_h LG[h*128+idx[row][h]][c] + const2[c]
__global__ __launch_bounds__(256) void final_k(
    const float* __restrict__ X, const float* __restrict__ Wbig,
    const float* __restrict__ LG, const int* __restrict__ idx,
    const float* __restrict__ const2, float* __restrict__ out)
{
    const int lane = threadIdx.x & 63;
    const int row = blockIdx.x * 4 + (threadIdx.x >> 6);
    if (row >= 608) return;
    const float4* x = (const float4*)(X + (long)row * 1792);
    float a0 = 0.f, a1 = 0.f;
    #pragma unroll
    for (int i = 0; i < 7; ++i) {
        const int d4 = lane + 64 * i;
        float4 xv = x[d4];
        const float4* w = (const float4*)(Wbig + (long)d4 * 8);
        float4 w0 = w[0], w1 = w[1];
        a0 += xv.x * w0.x + xv.y * w0.z + xv.z * w1.x + xv.w * w1.z;
        a1 += xv.x * w0.y + xv.y * w0.w + xv.z * w1.y + xv.w * w1.w;
    }
    #pragma unroll
    for (int off = 32; off; off >>= 1) { a0 += __shfl_down(a0, off); a1 += __shfl_down(a1, off); }
    if (lane == 0) {
        float r0 = a0 + const2[0], r1 = a1 + const2[1];
        #pragma unroll
        for (int h = 0; h < 4; ++h) {
            const int p = idx[row * 4 + h];
            r0 += LG[(h * 128 + p) * 2 + 0];
            r1 += LG[(h * 128 + p) * 2 + 1];
        }
        out[row * 2 + 0] = r0;
        out[row * 2 + 1] = r1;
    }
}

extern "C" void kernel_launch(void* const* d_in, const int* in_sizes, int n_in,
                              void* d_out, int out_size, void* d_ws, size_t ws_size,
                              hipStream_t stream)
{
    const float* X     = (const float*)d_in[0];
    const float* proto = (const float*)d_in[1];
    const float* Wq  = (const float*)d_in[3];
    const float* bq  = (const float*)d_in[4];
    const float* Wk  = (const float*)d_in[5];
    const float* bk  = (const float*)d_in[6];
    const float* Wv  = (const float*)d_in[7];
    const float* bv  = (const float*)d_in[8];
    const float* Wo  = (const float*)d_in[9];
    const float* bo  = (const float*)d_in[10];
    const float* Wfc = (const float*)d_in[11];
    const float* bfc = (const float*)d_in[12];
    const float* Wqa = (const float*)d_in[13];
    const float* bqa = (const float*)d_in[14];
    float* out = (float*)d_out;

    // workspace layout (floats)
    float* ws = (float*)d_ws;
    float* P      = ws;                       // 1,835,008 (partials, reused: KpVp -> Spart -> RFpart)
    float* P2     = P + 917504;               // second half for Vp partials
    float* Kp     = P + 1835008;              // 229,376
    float* Vp     = Kp + 229376;              // 229,376
    float* W2     = Vp + 229376;              // 917,504  [1792][512]
    float* sbias  = W2 + 917504;              // 512
    float* R      = sbias + 512;              // 917,504  [512][1792]
    float* RF     = R + 917504;               // 393,216  [512][768]
    float* LG     = RF + 393216;              // 1,024
    float* bvec   = LG + 1024;                // 768
    float* Wbig   = bvec + 768;               // 3,584
    float* const2 = Wbig + 3584;              // 2 (+2 pad)
    int*   idx    = (int*)(const2 + 4);       // 2,432 ints

    dim3 blk(256);

    // Kp = proto @ Wk (+bk), Vp = proto @ Wv (+bv)   [K-split 4]
    gemm_f32<false><<<dim3(28, 2, 4), blk, 0, stream>>>(proto, 1792, Wk, 1792, P,  1792, 128, 1792, 1792, 4, 0, 0, 0);
    gemm_f32<false><<<dim3(28, 2, 4), blk, 0, stream>>>(proto, 1792, Wv, 1792, P2, 1792, 128, 1792, 1792, 4, 0, 0, 0);
    reduce_add<<<dim3(896), blk, 0, stream>>>(P,  Kp, bk, 1792, 229376L, 4);
    reduce_add<<<dim3(896), blk, 0, stream>>>(P2, Vp, bv, 1792, 229376L, 4);

    // sbias[h][p] = bq_h . Kp[p]_h
    sbias_k<<<dim3(128), blk, 0, stream>>>(bq, Kp, sbias);

    // W2[:, h*128+p] = Wq_h @ Kp_h^T   (batched over 4 heads)
    gemm_f32<true><<<dim3(2, 28, 4), blk, 0, stream>>>(Wq, 1792, Kp, 1792, W2, 512, 1792, 128, 448, 1, 448, 448, 128);

    // scores partials = X @ W2   [K-split 4]
    gemm_f32<false><<<dim3(8, 10, 4), blk, 0, stream>>>(X, 1792, W2, 512, P, 512, 608, 512, 1792, 4, 0, 0, 0);

    // reduce + add sbias + argmax per (row, head)
    score_argmax<<<dim3(608), blk, 0, stream>>>(P, sbias, idx);

    // R[h*128+p] = Vp[p]_h @ Wo[h-rows]   (batched over heads)
    gemm_f32<false><<<dim3(28, 2, 4), blk, 0, stream>>>(Vp, 1792, Wo, 1792, R, 1792, 128, 1792, 448, 1,
                                                        448, 448L * 1792, 128L * 1792);

    // RF = R @ Wfc_bot   [K-split 2]
    gemm_f32<false><<<dim3(12, 8, 2), blk, 0, stream>>>(R, 1792, Wfc + 1792L * 768, 768, P, 768, 512, 768, 1792, 2, 0, 0, 0);
    reduce_add<<<dim3(1024), blk, 0, stream>>>(P, RF, nullptr, 768, 393216L, 2);

    // LG = RF @ Wqa
    lg_k<<<dim3(128), blk, 0, stream>>>(RF, Wqa, LG);

    // bvec = bfc + bo @ Wfc_bot ; Wbig = Wfc_top @ Wqa ; const2 = bvec@Wqa + bqa
    bvec_k<<<dim3(12), blk, 0, stream>>>(bo, Wfc, bfc, bvec);
    wbig_k<<<dim3(449), blk, 0, stream>>>(Wfc, Wqa, bvec, bqa, Wbig, const2);

    // logits
    final_k<<<dim3(152), blk, 0, stream>>>(X, Wbig, LG, idx, const2, out);
}

// Round 4
// 107.397 us; speedup vs baseline: 15.8190x; 1.9745x over previous
//
#include <hip/hip_runtime.h>

// B=16,S=38 -> ROWS=608; D=1792; H=4, DK=448; NP=128; INF=768
#define BM 64
#define BN 64
#define BK 16
#define LDT 68   // padded LDS leading dim (floats); 68*4B rows keep 16B alignment, no conflicts

// C = A[M,K] @ op(B), K-split into nsplit partials, optional batch bb via pointer strides.
// grid.z = nbatch*nsplit; bb = z/nsplit, kb = z%nsplit.
// nsplit>1: writes partial [kb][bb][M][N] starting at C. nsplit==1: C + sCb*bb with ldc.
template<bool TRANSB>
__global__ __launch_bounds__(256) void gemm_f32(
    const float* __restrict__ A, int lda,
    const float* __restrict__ B, int ldb,
    float* __restrict__ C, int ldc,
    int M, int N, int K, int nsplit,
    long sAb, long sBb, long sCb)
{
    const int nbb = gridDim.z / nsplit;
    const int kb = blockIdx.z % nsplit;
    const int bb = blockIdx.z / nsplit;
    A += sAb * bb;
    B += sBb * bb;
    const int Kc = K / nsplit;
    const int kbeg = kb * Kc;

    __shared__ float As[2][BK][LDT];
    __shared__ float Bs[2][BK][LDT];

    const int tid = threadIdx.x;
    const int tx = tid & 15, ty = tid >> 4;
    const int rowBase = blockIdx.y * BM;
    const int colBase = blockIdx.x * BN;

    // staging maps
    const int am  = tid >> 2;           // A row 0..63
    const int akq = (tid & 3) * 4;      // A k-quad
    const int bkr = tid >> 4;           // B k-row (TRANSB=false) 0..15
    const int bcq = (tid & 15) * 4;     // B col-quad
    const int bn  = tid >> 2;           // B n-row (TRANSB=true) 0..63
    const int bkq = (tid & 3) * 4;

    const long arow = (long)(rowBase + am) * lda;
    const bool aok = (rowBase + am) < M;

    auto loadA = [&](int k0) {
        float4 v = make_float4(0.f, 0.f, 0.f, 0.f);
        if (aok) v = *(const float4*)&A[arow + k0 + akq];
        return v;
    };
    auto loadB = [&](int k0) {
        if (!TRANSB) return *(const float4*)&B[(long)(k0 + bkr) * ldb + colBase + bcq];
        else         return *(const float4*)&B[(long)(colBase + bn) * ldb + k0 + bkq];
    };
    auto stage = [&](int buf, float4 av, float4 bv) {
        As[buf][akq + 0][am] = av.x; As[buf][akq + 1][am] = av.y;
        As[buf][akq + 2][am] = av.z; As[buf][akq + 3][am] = av.w;
        if (!TRANSB) {
            *(float4*)&Bs[buf][bkr][bcq] = bv;
        } else {
            Bs[buf][bkq + 0][bn] = bv.x; Bs[buf][bkq + 1][bn] = bv.y;
            Bs[buf][bkq + 2][bn] = bv.z; Bs[buf][bkq + 3][bn] = bv.w;
        }
    };

    float acc[4][4] = {};
    float4 av = loadA(kbeg), bv = loadB(kbeg);
    stage(0, av, bv);
    __syncthreads();

    const int nk = Kc / BK;
    for (int t = 0; t < nk; ++t) {
        const int cur = t & 1;
        const bool more = (t + 1 < nk);
        if (more) { av = loadA(kbeg + (t + 1) * BK); bv = loadB(kbeg + (t + 1) * BK); }
        #pragma unroll
        for (int kk = 0; kk < BK; ++kk) {
            float a[4], b[4];
            *(float4*)a = *(const float4*)&As[cur][kk][ty * 4];
            *(float4*)b = *(const float4*)&Bs[cur][kk][tx * 4];
            #pragma unroll
            for (int i = 0; i < 4; ++i)
                #pragma unroll
                for (int j = 0; j < 4; ++j)
                    acc[i][j] = fmaf(a[i], b[j], acc[i][j]);
        }
        if (more) stage(cur ^ 1, av, bv);
        __syncthreads();
    }

    float* Cw; int wldc;
    if (nsplit > 1) { Cw = C + ((long)kb * nbb + bb) * (long)M * N; wldc = N; }
    else            { Cw = C + sCb * bb; wldc = ldc; }
    #pragma unroll
    for (int i = 0; i < 4; ++i) {
        const int row = rowBase + ty * 4 + i;
        if (row >= M) continue;
        float4 v = make_float4(acc[i][0], acc[i][1], acc[i][2], acc[i][3]);
        *(float4*)&Cw[(long)row * wldc + colBase + tx * 4] = v;
    }
}

// out[i] = sum_z part[z*sz+i] (+ bias[i%N])
__global__ __launch_bounds__(256) void reduce_add(
    const float* __restrict__ part, float* __restrict__ out,
    const float* __restrict__ bias, int N, long sz, int nsplit)
{
    long i = (long)blockIdx.x * 256 + threadIdx.x;
    const long stride = (long)gridDim.x * 256;
    for (; i < sz; i += stride) {
        float s = 0.f;
        for (int z = 0; z < nsplit; ++z) s += part[z * sz + i];
        if (bias) s += bias[i % N];
        out[i] = s;
    }
}

// sbias[h*128+p] = dot(bq_h, Kp[p]_h) over 448
__global__ __launch_bounds__(256) void sbias_k(
    const float* __restrict__ bq, const float* __restrict__ Kp,
    float* __restrict__ sbias)
{
    const int lane = threadIdx.x & 63;
    const int unit = blockIdx.x * 4 + (threadIdx.x >> 6);
    if (unit >= 512) return;
    const int h = unit >> 7, p = unit & 127;
    const float* kr = Kp + (long)p * 1792 + h * 448;
    const float* bh = bq + h * 448;
    float s = 0.f;
    #pragma unroll
    for (int i = 0; i < 7; ++i) s = fmaf(bh[lane + 64 * i], kr[lane + 64 * i], s);
    #pragma unroll
    for (int off = 32; off; off >>= 1) s += __shfl_down(s, off);
    if (lane == 0) sbias[unit] = s;
}

// per (row,h): sum 8 K-split partials over 128 protos + sbias -> argmax index
__global__ __launch_bounds__(256) void score_argmax(
    const float* __restrict__ Sp,      // [8][4][608][128]
    const float* __restrict__ sbias,   // [4][128]
    int* __restrict__ idx)             // [608][4]
{
    const int lane = threadIdx.x & 63;
    const int unit = blockIdx.x * 4 + (threadIdx.x >> 6);
    if (unit >= 608 * 4) return;
    const int row = unit >> 2, h = unit & 3;
    float s0 = sbias[h * 128 + lane];
    float s1 = sbias[h * 128 + lane + 64];
    #pragma unroll
    for (int z = 0; z < 8; ++z) {
        const long base = ((long)(z * 4 + h) * 608 + row) * 128;
        s0 += Sp[base + lane];
        s1 += Sp[base + lane + 64];
    }
    float best = s0; int bi = lane;
    if (s1 > best) { best = s1; bi = lane + 64; }
    #pragma unroll
    for (int off = 32; off; off >>= 1) {
        float ov = __shfl_down(best, off);
        int   oi = __shfl_down(bi, off);
        if (ov > best || (ov == best && oi < bi)) { best = ov; bi = oi; }
    }
    if (lane == 0) idx[row * 4 + h] = bi;
}

// out[m*2+c] = sum_k A[m*lda+k] * W[k*2+c], for m in [0,Munits). K % 256 == 0.
__global__ __launch_bounds__(256) void colvec2_k(
    const float* __restrict__ A, int lda,
    const float* __restrict__ W, float* __restrict__ out,
    int Munits, int K)
{
    const int lane = threadIdx.x & 63;
    const int m = blockIdx.x * 4 + (threadIdx.x >> 6);
    if (m >= Munits) return;
    const float4* a = (const float4*)(A + (long)m * lda);
    float a0 = 0.f, a1 = 0.f;
    for (int i = 0; i < K / 256; ++i) {
        const int d4 = lane + 64 * i;
        float4 xv = a[d4];
        const float4* w = (const float4*)(W + (long)d4 * 8);
        float4 w0 = w[0], w1 = w[1];
        a0 += xv.x * w0.x + xv.y * w0.z + xv.z * w1.x + xv.w * w1.z;
        a1 += xv.x * w0.y + xv.y * w0.w + xv.z * w1.y + xv.w * w1.w;
    }
    #pragma unroll
    for (int off = 32; off; off >>= 1) { a0 += __shfl_down(a0, off); a1 += __shfl_down(a1, off); }
    if (lane == 0) { out[m * 2 + 0] = a0; out[m * 2 + 1] = a1; }
}

// WvWoQ[h][d][c] = sum_{j<448} Wv[d][h*448+j] * WoQ[(h*448+j)*2+c]
__global__ __launch_bounds__(256) void wvwoq_k(
    const float* __restrict__ Wv, const float* __restrict__ WoQ,
    float* __restrict__ out)
{
    const int lane = threadIdx.x & 63;
    const int d = blockIdx.x * 4 + (threadIdx.x >> 6);
    const int h = blockIdx.y;
    float s0 = 0.f, s1 = 0.f;
    const float* wr = Wv + (long)d * 1792 + h * 448;
    const float* wq = WoQ + h * 448 * 2;
    #pragma unroll
    for (int i = 0; i < 7; ++i) {
        const int j = lane + 64 * i;
        const float v = wr[j];
        s0 = fmaf(v, wq[j * 2 + 0], s0);
        s1 = fmaf(v, wq[j * 2 + 1], s1);
    }
    #pragma unroll
    for (int off = 32; off; off >>= 1) { s0 += __shfl_down(s0, off); s1 += __shfl_down(s1, off); }
    if (lane == 0) {
        out[((long)h * 1792 + d) * 2 + 0] = s0;
        out[((long)h * 1792 + d) * 2 + 1] = s1;
    }
}

// units 0..3: cv[h][c] = bv_h @ WoQ_h ; unit 4: const2 = bqa + bfc@Wqa + bo@WfbQ
__global__ __launch_bounds__(256) void bias_k(
    const float* __restrict__ bv, const float* __restrict__ WoQ,
    const float* __restrict__ bfc, const float* __restrict__ Wqa,
    const float* __restrict__ bo, const float* __restrict__ WfbQ,
    const float* __restrict__ bqa,
    float* __restrict__ cv, float* __restrict__ const2)
{
    const int lane = threadIdx.x & 63;
    const int unit = blockIdx.x * 4 + (threadIdx.x >> 6);
    if (unit > 4) return;
    float s0 = 0.f, s1 = 0.f;
    if (unit < 4) {
        const int h = unit;
        #pragma unroll
        for (int i = 0; i < 7; ++i) {
            const int j = h * 448 + lane + 64 * i;
            const float v = bv[j];
            s0 = fmaf(v, WoQ[j * 2 + 0], s0);
            s1 = fmaf(v, WoQ[j * 2 + 1], s1);
        }
    } else {
        for (int k = lane; k < 1792; k += 64) {
            if (k < 768) {
                s0 = fmaf(bfc[k], Wqa[k * 2 + 0], s0);
                s1 = fmaf(bfc[k], Wqa[k * 2 + 1], s1);
            }
            s0 = fmaf(bo[k], WfbQ[k * 2 + 0], s0);
            s1 = fmaf(bo[k], WfbQ[k * 2 + 1], s1);
        }
    }
    #pragma unroll
    for (int off = 32; off; off >>= 1) { s0 += __shfl_down(s0, off); s1 += __shfl_down(s1, off); }
    if (lane == 0) {
        if (unit < 4) { cv[unit * 2 + 0] = s0; cv[unit * 2 + 1] = s1; }
        else          { const2[0] = s0 + bqa[0]; const2[1] = s1 + bqa[1]; }
    }
}

// LG[h][p][c] = proto[p] @ WvWoQ[h] + cv[h][c]
__global__ __launch_bounds__(256) void lg_k(
    const float* __restrict__ proto, const float* __restrict__ WvWoQ,
    const float* __restrict__ cv, float* __restrict__ LG)
{
    const int lane = threadIdx.x & 63;
    const int p = blockIdx.x * 4 + (threadIdx.x >> 6);
    const int h = blockIdx.y;
    const float4* a = (const float4*)(proto + (long)p * 1792);
    const float* W = WvWoQ + (long)h * 1792 * 2;
    float a0 = 0.f, a1 = 0.f;
    #pragma unroll
    for (int i = 0; i < 7; ++i) {
        const int d4 = lane + 64 * i;
        float4 xv = a[d4];
        const float4* w = (const float4*)(W + (long)d4 * 8);
        float4 w0 = w[0], w1 = w[1];
        a0 += xv.x * w0.x + xv.y * w0.z + xv.z * w1.x + xv.w * w1.z;
        a1 += xv.x * w0.y + xv.y * w0.w + xv.z * w1.y + xv.w * w1.w;
    }
    #pragma unroll
    for (int off = 32; off; off >>= 1) { a0 += __shfl_down(a0, off); a1 += __shfl_down(a1, off); }
    if (lane == 0) {
        LG[(h * 128 + p) * 2 + 0] = a0 + cv[h * 2 + 0];
        LG[(h * 128 + p) * 2 + 1] = a1 + cv[h * 2 + 1];
    }
}

// logits[row][c] = X[row]@Wbig[:,c] + sum_h LG[h][idx[row][h]][c] + const2[c]
__global__ __launch_bounds__(256) void final_k(
    const float* __restrict__ X, const float* __restrict__ Wbig,
    const float* __restrict__ LG, const int* __restrict__ idx,
    const float* __restrict__ const2, float* __restrict__ out)
{
    const int lane = threadIdx.x & 63;
    const int row = blockIdx.x * 4 + (threadIdx.x >> 6);
    if (row >= 608) return;
    const float4* x = (const float4*)(X + (long)row * 1792);
    float a0 = 0.f, a1 = 0.f;
    #pragma unroll
    for (int i = 0; i < 7; ++i) {
        const int d4 = lane + 64 * i;
        float4 xv = x[d4];
        const float4* w = (const float4*)(Wbig + (long)d4 * 8);
        float4 w0 = w[0], w1 = w[1];
        a0 += xv.x * w0.x + xv.y * w0.z + xv.z * w1.x + xv.w * w1.z;
        a1 += xv.x * w0.y + xv.y * w0.w + xv.z * w1.y + xv.w * w1.w;
    }
    #pragma unroll
    for (int off = 32; off; off >>= 1) { a0 += __shfl_down(a0, off); a1 += __shfl_down(a1, off); }
    if (lane == 0) {
        float r0 = a0 + const2[0], r1 = a1 + const2[1];
        #pragma unroll
        for (int h = 0; h < 4; ++h) {
            const int p = idx[row * 4 + h];
            r0 += LG[(h * 128 + p) * 2 + 0];
            r1 += LG[(h * 128 + p) * 2 + 1];
        }
        out[row * 2 + 0] = r0;
        out[row * 2 + 1] = r1;
    }
}

extern "C" void kernel_launch(void* const* d_in, const int* in_sizes, int n_in,
                              void* d_out, int out_size, void* d_ws, size_t ws_size,
                              hipStream_t stream)
{
    const float* X     = (const float*)d_in[0];   // [608,1792]
    const float* proto = (const float*)d_in[1];   // [128,1792]
    const float* Wq  = (const float*)d_in[3];
    const float* bq  = (const float*)d_in[4];
    const float* Wk  = (const float*)d_in[5];
    const float* bk  = (const float*)d_in[6];
    const float* Wv  = (const float*)d_in[7];
    const float* bv  = (const float*)d_in[8];
    const float* Wo  = (const float*)d_in[9];
    const float* bo  = (const float*)d_in[10];
    const float* Wfc = (const float*)d_in[11];    // [3584,768]
    const float* bfc = (const float*)d_in[12];
    const float* Wqa = (const float*)d_in[13];    // [768,2]
    const float* bqa = (const float*)d_in[14];
    float* out = (float*)d_out;

    // workspace (floats)
    float* ws = (float*)d_ws;
    float* P      = ws;                 // 2,490,368 max (partials, reused)
    float* Kp     = P + 2490368;        // 229,376  [128][1792]
    float* W2b    = Kp + 229376;        // 917,504  [4][1792][128]
    float* sbias  = W2b + 917504;       // 512
    float* WbigB  = sbias + 512;        // 7,168    [3584][2]  (top=Wbig, bottom=WfbQ)
    float* WoQ    = WbigB + 7168;       // 3,584    [1792][2]
    float* WvWoQ  = WoQ + 3584;         // 14,336   [4][1792][2]
    float* LG     = WvWoQ + 14336;      // 1,024    [4][128][2]
    float* cv     = LG + 1024;          // 8
    float* const2 = cv + 8;             // 2 (+6 pad)
    int*   idx    = (int*)(const2 + 8); // 2,432 ints
    float* WfbQ   = WbigB + 1792 * 2;

    dim3 blk(256);

    // ---- score path (fp32, argmax-exact) ----
    // Kp partials = proto @ Wk  [K-split 8]
    gemm_f32<false><<<dim3(28, 2, 8), blk, 0, stream>>>(
        proto, 1792, Wk, 1792, P, 0, 128, 1792, 1792, 8, 0, 0, 0);
    reduce_add<<<dim3(896), blk, 0, stream>>>(P, Kp, bk, 1792, 229376L, 8);
    sbias_k<<<dim3(128), blk, 0, stream>>>(bq, Kp, sbias);

    // W2 partials: per head h, Wq_h[1792x448] @ Kp_h^T -> [1792][128]  [batch 4, K-split 2]
    gemm_f32<true><<<dim3(2, 28, 8), blk, 0, stream>>>(
        Wq, 1792, Kp, 1792, P, 0, 1792, 128, 448, 2, 448, 448, 0);
    reduce_add<<<dim3(1024), blk, 0, stream>>>(P, W2b, nullptr, 1, 917504L, 2);

    // Sc partials: X @ W2b[h]  [batch 4, K-split 8] -> [8][4][608][128]
    gemm_f32<false><<<dim3(2, 10, 32), blk, 0, stream>>>(
        X, 1792, W2b, 128, P, 0, 608, 128, 1792, 8, 0, 229376L, 0);
    score_argmax<<<dim3(608), blk, 0, stream>>>(P, sbias, idx);

    // ---- value path, folded to 2 output columns (all tiny) ----
    // WbigB[0:1792]=Wfc_top@Wqa (=Wbig), WbigB[1792:3584]=Wfc_bot@Wqa (=WfbQ)
    colvec2_k<<<dim3(896), blk, 0, stream>>>(Wfc, 768, Wqa, WbigB, 3584, 768);
    // WoQ = Wo @ WfbQ
    colvec2_k<<<dim3(448), blk, 0, stream>>>(Wo, 1792, WfbQ, WoQ, 1792, 1792);
    // WvWoQ[h] = Wv[:,h-cols] @ WoQ[h-rows]
    wvwoq_k<<<dim3(448, 4), blk, 0, stream>>>(Wv, WoQ, WvWoQ);
    // cv[h] = bv_h@WoQ_h ; const2 = bqa + bfc@Wqa + bo@WfbQ
    bias_k<<<dim3(2), blk, 0, stream>>>(bv, WoQ, bfc, Wqa, bo, WfbQ, bqa, cv, const2);
    // LG[h][p] = proto[p] @ WvWoQ[h] + cv[h]
    lg_k<<<dim3(32, 4), blk, 0, stream>>>(proto, WvWoQ, cv, LG);

    // ---- final ----
    final_k<<<dim3(152), blk, 0, stream>>>(X, WbigB, LG, idx, const2, out);
}